// Round 10
// baseline (528.058 us; speedup 1.0000x reference)
//
#include <hip/hip_runtime.h>

#define N_NODES 50000
#define N_EDGES 800000
#define IN_CH 64
#define HID 128
#define NBKT 782        // ceil(50000/64) buckets of 64 dst-nodes
#define BCAP 1536       // bucket capacity: mean 1023, sigma 32 -> +16 sigma

typedef short short8 __attribute__((ext_vector_type(8)));
typedef float f32x4 __attribute__((ext_vector_type(4)));

static __device__ __forceinline__ unsigned short f2bf(float f) {
    unsigned u = __float_as_uint(f);
    u += 0x7FFF + ((u >> 16) & 1);   // RNE
    return (unsigned short)(u >> 16);
}
static __device__ __forceinline__ float bflo(unsigned v) { return __uint_as_float(v << 16); }
static __device__ __forceinline__ float bfhi(unsigned v) { return __uint_as_float(v & 0xFFFF0000u); }

// ---------------- fp32 -> bf16 conversion ----------------

__global__ __launch_bounds__(256) void k_cvt(const float* __restrict__ src,
                                             unsigned short* __restrict__ dst, int n4) {
    int i = blockIdx.x * 256 + threadIdx.x;
    if (i < n4) {
        float4 v = ((const float4*)src)[i];
        unsigned lo = f2bf(v.x) | ((unsigned)f2bf(v.y) << 16);
        unsigned hi = f2bf(v.z) | ((unsigned)f2bf(v.w) << 16);
        ((uint2*)dst)[i] = make_uint2(lo, hi);
    }
}

__global__ __launch_bounds__(256) void k_cvt_w(const float* __restrict__ W1l, const float* __restrict__ W1r,
                                               const float* __restrict__ W2l, const float* __restrict__ W2r,
                                               const float* __restrict__ Wrec, unsigned short* __restrict__ dst) {
    int i = blockIdx.x * 256 + threadIdx.x;   // float4 units, total 14336
    int e = i * 4;
    if (e >= 57344) return;
    const float* src; int off;
    if (e < 8192)       { src = W1l;  off = 0; }
    else if (e < 16384) { src = W1r;  off = 8192; }
    else if (e < 32768) { src = W2l;  off = 16384; }
    else if (e < 49152) { src = W2r;  off = 32768; }
    else                { src = Wrec; off = 49152; }
    float4 v = *(const float4*)(src + (e - off));
    unsigned lo = f2bf(v.x) | ((unsigned)f2bf(v.y) << 16);
    unsigned hi = f2bf(v.z) | ((unsigned)f2bf(v.w) << 16);
    *(uint2*)(dst + e) = make_uint2(lo, hi);
}

// ---------------- bucketed CSR build ----------------
// pass A: scatter src|dst<<32 into 782 dst-buckets (streaming tails, 8B entries)

__global__ __launch_bounds__(256) void k_bfill(const int* __restrict__ ei,
                                               int* __restrict__ bcur,
                                               unsigned long long* __restrict__ bbuf) {
    int e = blockIdx.x * 256 + threadIdx.x;
    if (e < N_EDGES) {
        int s = ei[e];
        int d = ei[N_EDGES + e];
        if ((unsigned)d < N_NODES && (unsigned)s < N_NODES) {
            int b = (unsigned)d >> 6;
            int pos = atomicAdd(&bcur[b], 1);
            if (pos < BCAP)
                bbuf[(size_t)b * BCAP + pos] = (unsigned long long)(unsigned)s |
                                               ((unsigned long long)(unsigned)d << 32);
        }
    }
}

// scan 782 bucket sizes -> bucket bases; write grand total
__global__ __launch_bounds__(1024) void k_bscan(const int* __restrict__ bcur,
                                                int* __restrict__ bbase,
                                                int* __restrict__ offs) {
    int tid = threadIdx.x;
    int raw = (tid < NBKT) ? bcur[tid] : 0;
    int v = raw < BCAP ? raw : BCAP;
    if (tid >= NBKT) v = 0;
    int lane = tid & 63, wv = tid >> 6;
    int s = v;
    #pragma unroll
    for (int d = 1; d < 64; d <<= 1) {
        int t = __shfl_up(s, d);
        if (lane >= d) s += t;
    }
    __shared__ int wsum[16];
    if (lane == 63) wsum[wv] = s;
    __syncthreads();
    if (tid < 16) {
        int w = wsum[tid];
        #pragma unroll
        for (int d = 1; d < 16; d <<= 1) {
            int t = __shfl_up(w, d);
            if (tid >= d) w += t;
        }
        wsum[tid] = w;
    }
    __syncthreads();
    int incl = s + (wv > 0 ? wsum[wv - 1] : 0);
    if (tid < NBKT) bbase[tid] = incl - v;
    if (tid == NBKT - 1) offs[N_NODES] = incl;
}

// pass B: per-bucket LDS histogram + scan + scatter; writes offs[] and csr[]
__global__ __launch_bounds__(256) void k_bcsr(const unsigned long long* __restrict__ bbuf,
                                              const int* __restrict__ bcur,
                                              const int* __restrict__ bbase,
                                              int* __restrict__ offs,
                                              int* __restrict__ csr) {
    int b = blockIdx.x;
    int size = bcur[b]; if (size > BCAP) size = BCAP;
    int base = bbase[b];
    __shared__ int lcnt[64];
    __shared__ int lexcl[64];
    int tid = threadIdx.x;
    if (tid < 64) lcnt[tid] = 0;
    __syncthreads();
    for (int i = tid; i < size; i += 256) {
        unsigned long long E = __builtin_nontemporal_load(&bbuf[(size_t)b * BCAP + i]);
        atomicAdd(&lcnt[(unsigned)(E >> 32) & 63], 1);
    }
    __syncthreads();
    if (tid < 64) {
        int vv = lcnt[tid];
        int ss = vv;
        #pragma unroll
        for (int d = 1; d < 64; d <<= 1) {
            int t = __shfl_up(ss, d);
            if (tid >= d) ss += t;
        }
        lexcl[tid] = ss - vv;
        int node = b * 64 + tid;
        if (node < N_NODES) offs[node] = base + ss - vv;
    }
    __syncthreads();
    if (tid < 64) lcnt[tid] = lexcl[tid];   // cursor
    __syncthreads();
    for (int i = tid; i < size; i += 256) {
        unsigned long long E = __builtin_nontemporal_load(&bbuf[(size_t)b * BCAP + i]);
        int p = atomicAdd(&lcnt[(unsigned)(E >> 32) & 63], 1);
        csr[base + p] = (int)(unsigned)(E & 0xFFFFFFFFull);
    }
}

// ---------------- channel-split mean aggregation (32 ch = 64B per dispatch) ----------------
// wave per node; 4 edge-groups x 16 lanes; 2 ch per lane; nt loads for csr stream.

template <int CH>
__global__ __launch_bounds__(256) void k_agg_cs(const unsigned short* __restrict__ X,
                                                const int* __restrict__ csr,
                                                const int* __restrict__ offs,
                                                unsigned short* __restrict__ out,
                                                int c0) {
    int wid = (blockIdx.x * 256 + threadIdx.x) >> 6;
    int lane = threadIdx.x & 63;
    if (wid >= N_NODES) return;
    int beg = offs[wid], end = offs[wid + 1];
    int degn = end - beg;
    float inv = 1.0f / (float)(degn > 0 ? degn : 1);
    int g = lane >> 4, hl = lane & 15;
    float sx = 0.f, sy = 0.f;
    for (int e = beg + g; e < end; e += 4) {
        int idx = __builtin_nontemporal_load(&csr[e]);
        unsigned v = *(const unsigned*)(X + (size_t)idx * CH + c0 + hl * 2);
        sx += bflo(v); sy += bfhi(v);
    }
    sx += __shfl_xor(sx, 16); sy += __shfl_xor(sy, 16);
    sx += __shfl_xor(sx, 32); sy += __shfl_xor(sy, 32);
    if (g == 0) {
        unsigned o = f2bf(sx * inv) | ((unsigned)f2bf(sy * inv) << 16);
        *(unsigned*)(out + (size_t)wid * CH + c0 + hl * 2) = o;
    }
}

// ---------------- bf16 MFMA GEMM, W staged in LDS (XOR-swizzled) ----------------
// Block: 4 waves x 16 rows = 64 rows. acc over (DUAL?2:1) phases of K1 each.

template <int NOUT, int K1, bool DUAL, bool RELU, bool WF32, bool WBF16>
__global__ __launch_bounds__(256) void k_gemm_mfma(const unsigned short* __restrict__ A0,
                                                   const unsigned short* __restrict__ A1,
                                                   const unsigned short* __restrict__ W0,
                                                   const unsigned short* __restrict__ W1,
                                                   const float* __restrict__ bias,
                                                   float* __restrict__ out,
                                                   unsigned short* __restrict__ outb) {
    constexpr int NF = NOUT / 16;
    constexpr int NPH = DUAL ? 2 : 1;
    __shared__ char wlds[NOUT * K1 * 2];   // 16KB or 32KB
    int tid = threadIdx.x;
    int lane = tid & 63;
    int wv = tid >> 6;
    int m0 = blockIdx.x * 64 + wv * 16;
    int col16 = lane & 15;
    int kg = lane >> 4;
    int arow = m0 + col16;
    if (arow >= N_NODES) arow = N_NODES - 1;   // safe load; store guarded

    f32x4 acc[NF] = {};

    #pragma unroll
    for (int ph = 0; ph < NPH; ph++) {
        const unsigned short* Wp = ph ? W1 : W0;
        const unsigned short* Ap = ph ? A1 : A0;
        if (ph) __syncthreads();   // previous phase's LDS reads done
        // stage W: row j, col c (8 bf16 = 16B chunks), byte-XOR swizzle on row
        constexpr int CHUNKS = NOUT * K1 / 8;
        #pragma unroll
        for (int it = 0; it < CHUNKS / 256; it++) {
            int ci = tid + it * 256;
            int j = ci / (K1 / 8);
            int c = (ci % (K1 / 8)) * 8;
            short8 w = *(const short8*)(Wp + (size_t)j * K1 + c);
            int byte = ((j * K1 + c) * 2) ^ ((j & 7) << 4);
            *(short8*)(wlds + byte) = w;
        }
        __syncthreads();
        #pragma unroll
        for (int ks = 0; ks < K1 / 32; ks++) {
            int kk = ks * 32;
            short8 a = *(const short8*)(Ap + (size_t)arow * K1 + kk + kg * 8);
            #pragma unroll
            for (int j = 0; j < NF; j++) {
                int row = j * 16 + col16;
                int byte = ((row * K1 + kk + kg * 8) * 2) ^ ((row & 7) << 4);
                short8 b = *(const short8*)(wlds + byte);
                acc[j] = __builtin_amdgcn_mfma_f32_16x16x32_bf16(a, b, acc[j], 0, 0, 0);
            }
        }
    }

    // C/D layout: col = lane&15, row = (lane>>4)*4 + reg   [verified, learn_hip m89]
    int col = lane & 15;
    int r0 = (lane >> 4) * 4;
    #pragma unroll
    for (int j = 0; j < NF; j++) {
        float bv = bias[j * 16 + col];
        #pragma unroll
        for (int r = 0; r < 4; r++) {
            int grow = m0 + r0 + r;
            if (grow < N_NODES) {
                float v = acc[j][r] + bv;
                if (RELU) v = fmaxf(v, 0.f);
                if (WF32)  out[(size_t)grow * NOUT + j * 16 + col] = v;
                if (WBF16) outb[(size_t)grow * NOUT + j * 16 + col] = f2bf(v);
            }
        }
    }
}

// ---------------- launch ----------------

extern "C" void kernel_launch(void* const* d_in, const int* in_sizes, int n_in,
                              void* d_out, int out_size, void* d_ws, size_t ws_size,
                              hipStream_t stream) {
    const float* x    = (const float*)d_in[0];
    const int*   ei   = (const int*)d_in[1];
    const float* W1l  = (const float*)d_in[2];
    const float* b1l  = (const float*)d_in[3];
    const float* W1r  = (const float*)d_in[4];
    const float* W2l  = (const float*)d_in[5];
    const float* b2l  = (const float*)d_in[6];
    const float* W2r  = (const float*)d_in[7];
    const float* Wrec = (const float*)d_in[8];
    const float* brec = (const float*)d_in[9];

    float* z    = (float*)d_out;                          // [N,128]
    float* xrec = (float*)d_out + (size_t)N_NODES * HID;  // [N,64]

    // workspace layout (peak ~51 MB), lifetimes annotated
    char* ws = (char*)d_ws;
    int*   bcur  = (int*)(ws);                    // 782 ints
    int*   bbase = (int*)(ws + (4u << 10));       // 782 ints
    int*   offs  = (int*)(ws + (16u << 10));      // 50001 ints
    int*   csr   = (int*)(ws + (512u << 10));     // 3.2 MB       (until agg128)
    unsigned long long* bbuf = (unsigned long long*)(ws + (4u << 20)); // 9.6 MB (dead after bcsr)
    unsigned short* zb     = (unsigned short*)(ws + (4u << 20));   // 12.8 MB (gemm2->gemm3, reuses bbuf)
    unsigned short* mean1b = (unsigned short*)(ws + (17u << 20));  // 6.4 MB  (agg64->gemm1)
    unsigned short* mean2b = (unsigned short*)(ws + (17u << 20));  // 12.8 MB (agg128->gemm2, reuses mean1b)
    unsigned short* wb     = (unsigned short*)(ws + (30u << 20));  // 114 KB bf16 weights
    unsigned short* xb     = (unsigned short*)(ws + (31u << 20));  // 6.4 MB
    unsigned short* hb     = (unsigned short*)(ws + (38u << 20));  // 12.8 MB

    unsigned short* W1lb  = wb;
    unsigned short* W1rb  = wb + 8192;
    unsigned short* W2lb  = wb + 16384;
    unsigned short* W2rb  = wb + 32768;
    unsigned short* Wrecb = wb + 49152;

    (void)hipMemsetAsync(bcur, 0, NBKT * sizeof(int), stream);

    int egrid = (N_EDGES + 255) / 256;
    int ngrid = (N_NODES + 63) / 64;   // 782
    int agrid = N_NODES / 4;           // 12500

    k_cvt_w<<<56, 256, 0, stream>>>(W1l, W1r, W2l, W2r, Wrec, wb);
    k_cvt<<<(800000 + 255) / 256, 256, 0, stream>>>(x, xb, 800000);

    k_bfill<<<egrid, 256, 0, stream>>>(ei, bcur, bbuf);
    k_bscan<<<1, 1024, 0, stream>>>(bcur, bbase, offs);
    k_bcsr<<<NBKT, 256, 0, stream>>>(bbuf, bcur, bbase, offs, csr);

    for (int c = 0; c < 64; c += 32)
        k_agg_cs<64><<<agrid, 256, 0, stream>>>(xb, csr, offs, mean1b, c);
    k_gemm_mfma<128, 64, true, true, false, true>
        <<<ngrid, 256, 0, stream>>>(mean1b, xb, W1lb, W1rb, b1l, nullptr, hb);
    for (int c = 0; c < 128; c += 32)
        k_agg_cs<128><<<agrid, 256, 0, stream>>>(hb, csr, offs, mean2b, c);
    k_gemm_mfma<128, 128, true, false, true, true>
        <<<ngrid, 256, 0, stream>>>(mean2b, hb, W2lb, W2rb, b2l, z, zb);
    k_gemm_mfma<64, 128, false, false, true, false>
        <<<ngrid, 256, 0, stream>>>(zb, nullptr, Wrecb, nullptr, brec, xrec, nullptr);
}

// Round 14
// 406.733 us; speedup vs baseline: 1.2983x; 1.2983x over previous
//
#include <hip/hip_runtime.h>

#define N_NODES 50000
#define N_EDGES 800000
#define IN_CH 64
#define HID 128
#define NB_SCAN ((N_NODES + 255) / 256)   // 196 blocks

typedef short short8 __attribute__((ext_vector_type(8)));
typedef float f32x4 __attribute__((ext_vector_type(4)));

static __device__ __forceinline__ unsigned short f2bf(float f) {
    unsigned u = __float_as_uint(f);
    u += 0x7FFF + ((u >> 16) & 1);   // RNE
    return (unsigned short)(u >> 16);
}
static __device__ __forceinline__ float bflo(unsigned v) { return __uint_as_float(v << 16); }
static __device__ __forceinline__ float bfhi(unsigned v) { return __uint_as_float(v & 0xFFFF0000u); }

// ---------------- fp32 -> bf16 conversion ----------------

__global__ __launch_bounds__(256) void k_cvt(const float* __restrict__ src,
                                             unsigned short* __restrict__ dst, int n4) {
    int i = blockIdx.x * 256 + threadIdx.x;
    if (i < n4) {
        float4 v = ((const float4*)src)[i];
        unsigned lo = f2bf(v.x) | ((unsigned)f2bf(v.y) << 16);
        unsigned hi = f2bf(v.z) | ((unsigned)f2bf(v.w) << 16);
        ((uint2*)dst)[i] = make_uint2(lo, hi);
    }
}

__global__ __launch_bounds__(256) void k_cvt_w(const float* __restrict__ W1l, const float* __restrict__ W1r,
                                               const float* __restrict__ W2l, const float* __restrict__ W2r,
                                               const float* __restrict__ Wrec, unsigned short* __restrict__ dst) {
    int i = blockIdx.x * 256 + threadIdx.x;   // float4 units, total 14336
    int e = i * 4;
    if (e >= 57344) return;
    const float* src; int off;
    if (e < 8192)       { src = W1l;  off = 0; }
    else if (e < 16384) { src = W1r;  off = 8192; }
    else if (e < 32768) { src = W2l;  off = 16384; }
    else if (e < 49152) { src = W2r;  off = 32768; }
    else                { src = Wrec; off = 49152; }
    float4 v = *(const float4*)(src + (e - off));
    unsigned lo = f2bf(v.x) | ((unsigned)f2bf(v.y) << 16);
    unsigned hi = f2bf(v.z) | ((unsigned)f2bf(v.w) << 16);
    *(uint2*)(dst + e) = make_uint2(lo, hi);
}

// ---------------- CSR build (round-4 proven path) ----------------

__global__ __launch_bounds__(256) void k_deg(const int* __restrict__ ei, int* __restrict__ deg) {
    int e = blockIdx.x * 256 + threadIdx.x;
    if (e < N_EDGES) {
        int d = ei[N_EDGES + e];
        if ((unsigned)d < N_NODES) atomicAdd(&deg[d], 1);   // no-return atomic: fast
    }
}

__global__ __launch_bounds__(256) void k_scan1(const int* __restrict__ deg,
                                               int* __restrict__ excl,
                                               int* __restrict__ bsum) {
    int gid = blockIdx.x * 256 + threadIdx.x;
    int v = (gid < N_NODES) ? deg[gid] : 0;
    int lane = threadIdx.x & 63, wv = threadIdx.x >> 6;
    int s = v;
    #pragma unroll
    for (int d = 1; d < 64; d <<= 1) {
        int t = __shfl_up(s, d);
        if (lane >= d) s += t;
    }
    __shared__ int wsum[4];
    if (lane == 63) wsum[wv] = s;
    __syncthreads();
    int add = 0;
    #pragma unroll
    for (int w = 0; w < 4; w++) add += (w < wv) ? wsum[w] : 0;
    s += add;
    if (gid < N_NODES) excl[gid] = s - v;
    if (threadIdx.x == 255) bsum[blockIdx.x] = s;
}

__global__ __launch_bounds__(256) void k_scan2(const int* __restrict__ bsum,
                                               int* __restrict__ bpre,
                                               int* __restrict__ offs) {
    int tid = threadIdx.x;
    int v = (tid < NB_SCAN) ? bsum[tid] : 0;
    int lane = tid & 63, wv = tid >> 6;
    int s = v;
    #pragma unroll
    for (int d = 1; d < 64; d <<= 1) {
        int t = __shfl_up(s, d);
        if (lane >= d) s += t;
    }
    __shared__ int wsum[4];
    if (lane == 63) wsum[wv] = s;
    __syncthreads();
    int add = 0;
    #pragma unroll
    for (int w = 0; w < 4; w++) add += (w < wv) ? wsum[w] : 0;
    s += add;
    if (tid < NB_SCAN) bpre[tid] = s - v;
    if (tid == NB_SCAN - 1) offs[N_NODES] = s;
}

__global__ __launch_bounds__(256) void k_scan3(const int* __restrict__ excl,
                                               const int* __restrict__ bpre,
                                               int* __restrict__ offs) {
    int gid = blockIdx.x * 256 + threadIdx.x;
    if (gid < N_NODES) offs[gid] = excl[gid] + bpre[blockIdx.x];
}

__global__ __launch_bounds__(256) void k_fill(const int* __restrict__ ei, const int* __restrict__ offs,
                                              int* __restrict__ cursor, int* __restrict__ csr) {
    int e = blockIdx.x * 256 + threadIdx.x;
    if (e < N_EDGES) {
        int s = ei[e];
        int d = ei[N_EDGES + e];
        if ((unsigned)d < N_NODES && (unsigned)s < N_NODES) {
            int pos = atomicAdd(&cursor[d], 1);   // returning atomic, 50K addrs, ~16 hits each: OK
            csr[offs[d] + pos] = s;
        }
    }
}

// ---------------- channel-split mean aggregation (32 ch = 64B per dispatch) ----------------
// wave per node; 4 edge-groups x 16 lanes; 2 ch per lane; nt loads for csr stream.

template <int CH>
__global__ __launch_bounds__(256) void k_agg_cs(const unsigned short* __restrict__ X,
                                                const int* __restrict__ csr,
                                                const int* __restrict__ offs,
                                                unsigned short* __restrict__ out,
                                                int c0) {
    int wid = (blockIdx.x * 256 + threadIdx.x) >> 6;
    int lane = threadIdx.x & 63;
    if (wid >= N_NODES) return;
    int beg = offs[wid], end = offs[wid + 1];
    int degn = end - beg;
    float inv = 1.0f / (float)(degn > 0 ? degn : 1);
    int g = lane >> 4, hl = lane & 15;
    float sx = 0.f, sy = 0.f;
    for (int e = beg + g; e < end; e += 4) {
        int idx = __builtin_nontemporal_load(&csr[e]);
        unsigned v = *(const unsigned*)(X + (size_t)idx * CH + c0 + hl * 2);
        sx += bflo(v); sy += bfhi(v);
    }
    sx += __shfl_xor(sx, 16); sy += __shfl_xor(sy, 16);
    sx += __shfl_xor(sx, 32); sy += __shfl_xor(sy, 32);
    if (g == 0) {
        unsigned o = f2bf(sx * inv) | ((unsigned)f2bf(sy * inv) << 16);
        *(unsigned*)(out + (size_t)wid * CH + c0 + hl * 2) = o;
    }
}

// ---------------- bf16 MFMA GEMM, W staged in LDS (XOR-swizzled) ----------------
// Block: 4 waves x 16 rows = 64 rows. acc over (DUAL?2:1) phases of K1 each.

template <int NOUT, int K1, bool DUAL, bool RELU, bool WF32, bool WBF16>
__global__ __launch_bounds__(256) void k_gemm_mfma(const unsigned short* __restrict__ A0,
                                                   const unsigned short* __restrict__ A1,
                                                   const unsigned short* __restrict__ W0,
                                                   const unsigned short* __restrict__ W1,
                                                   const float* __restrict__ bias,
                                                   float* __restrict__ out,
                                                   unsigned short* __restrict__ outb) {
    constexpr int NF = NOUT / 16;
    constexpr int NPH = DUAL ? 2 : 1;
    __shared__ char wlds[NOUT * K1 * 2];   // 16KB or 32KB
    int tid = threadIdx.x;
    int lane = tid & 63;
    int wv = tid >> 6;
    int m0 = blockIdx.x * 64 + wv * 16;
    int col16 = lane & 15;
    int kg = lane >> 4;
    int arow = m0 + col16;
    if (arow >= N_NODES) arow = N_NODES - 1;   // safe load; store guarded

    f32x4 acc[NF] = {};

    #pragma unroll
    for (int ph = 0; ph < NPH; ph++) {
        const unsigned short* Wp = ph ? W1 : W0;
        const unsigned short* Ap = ph ? A1 : A0;
        if (ph) __syncthreads();   // previous phase's LDS reads done
        // stage W: row j, col c (8 bf16 = 16B chunks), byte-XOR swizzle on row
        constexpr int CHUNKS = NOUT * K1 / 8;
        #pragma unroll
        for (int it = 0; it < CHUNKS / 256; it++) {
            int ci = tid + it * 256;
            int j = ci / (K1 / 8);
            int c = (ci % (K1 / 8)) * 8;
            short8 w = *(const short8*)(Wp + (size_t)j * K1 + c);
            int byte = ((j * K1 + c) * 2) ^ ((j & 7) << 4);
            *(short8*)(wlds + byte) = w;
        }
        __syncthreads();
        #pragma unroll
        for (int ks = 0; ks < K1 / 32; ks++) {
            int kk = ks * 32;
            short8 a = *(const short8*)(Ap + (size_t)arow * K1 + kk + kg * 8);
            #pragma unroll
            for (int j = 0; j < NF; j++) {
                int row = j * 16 + col16;
                int byte = ((row * K1 + kk + kg * 8) * 2) ^ ((row & 7) << 4);
                short8 b = *(const short8*)(wlds + byte);
                acc[j] = __builtin_amdgcn_mfma_f32_16x16x32_bf16(a, b, acc[j], 0, 0, 0);
            }
        }
    }

    // C/D layout: col = lane&15, row = (lane>>4)*4 + reg   [verified, learn_hip m89]
    int col = lane & 15;
    int r0 = (lane >> 4) * 4;
    #pragma unroll
    for (int j = 0; j < NF; j++) {
        float bv = bias[j * 16 + col];
        #pragma unroll
        for (int r = 0; r < 4; r++) {
            int grow = m0 + r0 + r;
            if (grow < N_NODES) {
                float v = acc[j][r] + bv;
                if (RELU) v = fmaxf(v, 0.f);
                if (WF32)  out[(size_t)grow * NOUT + j * 16 + col] = v;
                if (WBF16) outb[(size_t)grow * NOUT + j * 16 + col] = f2bf(v);
            }
        }
    }
}

// ---------------- launch ----------------

extern "C" void kernel_launch(void* const* d_in, const int* in_sizes, int n_in,
                              void* d_out, int out_size, void* d_ws, size_t ws_size,
                              hipStream_t stream) {
    const float* x    = (const float*)d_in[0];
    const int*   ei   = (const int*)d_in[1];
    const float* W1l  = (const float*)d_in[2];
    const float* b1l  = (const float*)d_in[3];
    const float* W1r  = (const float*)d_in[4];
    const float* W2l  = (const float*)d_in[5];
    const float* b2l  = (const float*)d_in[6];
    const float* W2r  = (const float*)d_in[7];
    const float* Wrec = (const float*)d_in[8];
    const float* brec = (const float*)d_in[9];

    float* z    = (float*)d_out;                          // [N,128]
    float* xrec = (float*)d_out + (size_t)N_NODES * HID;  // [N,64]

    // workspace layout (peak ~52 MB), lifetimes annotated
    char* ws = (char*)d_ws;
    int*   deg    = (int*)(ws);                  // 200 KB
    int*   offs   = (int*)(ws + (256u << 10));   // 50001 ints
    int*   cursor = (int*)(ws + (512u << 10));
    int*   excl   = (int*)(ws + (768u << 10));
    int*   bsum   = (int*)(ws + (1024u << 10));  // 196 ints
    int*   bpre   = (int*)(ws + (1028u << 10));  // 196 ints
    int*   csr    = (int*)(ws + (2u << 20));     // 3.2 MB
    unsigned short* wb     = (unsigned short*)(ws + (5632u << 10));  // 114 KB bf16 weights
    unsigned short* xb     = (unsigned short*)(ws + (6u  << 20));    // [N,64]  6.4 MB
    unsigned short* mean1b = (unsigned short*)(ws + (13u << 20));    // [N,64]  (dead after gemm1)
    unsigned short* mean2b = (unsigned short*)(ws + (13u << 20));    // [N,128] reuses mean1b
    unsigned short* hb     = (unsigned short*)(ws + (26u << 20));    // [N,128] 12.8 MB
    unsigned short* zb     = (unsigned short*)(ws + (39u << 20));    // [N,128] 12.8 MB

    unsigned short* W1lb  = wb;
    unsigned short* W1rb  = wb + 8192;
    unsigned short* W2lb  = wb + 16384;
    unsigned short* W2rb  = wb + 32768;
    unsigned short* Wrecb = wb + 49152;

    (void)hipMemsetAsync(deg, 0, N_NODES * sizeof(int), stream);
    (void)hipMemsetAsync(cursor, 0, N_NODES * sizeof(int), stream);

    int egrid = (N_EDGES + 255) / 256;
    int ngrid = (N_NODES + 63) / 64;   // 782
    int agrid = N_NODES / 4;           // 12500

    k_cvt_w<<<56, 256, 0, stream>>>(W1l, W1r, W2l, W2r, Wrec, wb);
    k_cvt<<<(800000 + 255) / 256, 256, 0, stream>>>(x, xb, 800000);

    k_deg<<<egrid, 256, 0, stream>>>(ei, deg);
    k_scan1<<<NB_SCAN, 256, 0, stream>>>(deg, excl, bsum);
    k_scan2<<<1, 256, 0, stream>>>(bsum, bpre, offs);
    k_scan3<<<NB_SCAN, 256, 0, stream>>>(excl, bpre, offs);
    k_fill<<<egrid, 256, 0, stream>>>(ei, offs, cursor, csr);

    for (int c = 0; c < 64; c += 32)
        k_agg_cs<64><<<agrid, 256, 0, stream>>>(xb, csr, offs, mean1b, c);
    k_gemm_mfma<128, 64, true, true, false, true>
        <<<ngrid, 256, 0, stream>>>(mean1b, xb, W1lb, W1rb, b1l, nullptr, hb);
    for (int c = 0; c < 128; c += 32)
        k_agg_cs<128><<<agrid, 256, 0, stream>>>(hb, csr, offs, mean2b, c);
    k_gemm_mfma<128, 128, true, false, true, true>
        <<<ngrid, 256, 0, stream>>>(mean2b, hb, W2lb, W2rb, b2l, z, zb);
    k_gemm_mfma<64, 128, false, false, true, false>
        <<<ngrid, 256, 0, stream>>>(zb, nullptr, Wrecb, nullptr, brec, xrec, nullptr);
}

// Round 17
// 330.158 us; speedup vs baseline: 1.5994x; 1.2319x over previous
//
#include <hip/hip_runtime.h>

#define N_NODES 50000
#define N_EDGES 800000
#define IN_CH 64
#define HID 128
#define NB_SCAN ((N_NODES + 255) / 256)   // 196 blocks

typedef short short8 __attribute__((ext_vector_type(8)));
typedef float f32x4 __attribute__((ext_vector_type(4)));

static __device__ __forceinline__ unsigned short f2bf(float f) {
    unsigned u = __float_as_uint(f);
    u += 0x7FFF + ((u >> 16) & 1);   // RNE
    return (unsigned short)(u >> 16);
}
static __device__ __forceinline__ float bflo(unsigned v) { return __uint_as_float(v << 16); }
static __device__ __forceinline__ float bfhi(unsigned v) { return __uint_as_float(v & 0xFFFF0000u); }

// ---------------- fp32 -> bf16 conversion ----------------

__global__ __launch_bounds__(256) void k_cvt(const float* __restrict__ src,
                                             unsigned short* __restrict__ dst, int n4) {
    int i = blockIdx.x * 256 + threadIdx.x;
    if (i < n4) {
        float4 v = ((const float4*)src)[i];
        unsigned lo = f2bf(v.x) | ((unsigned)f2bf(v.y) << 16);
        unsigned hi = f2bf(v.z) | ((unsigned)f2bf(v.w) << 16);
        ((uint2*)dst)[i] = make_uint2(lo, hi);
    }
}

__global__ __launch_bounds__(256) void k_cvt_w(const float* __restrict__ W1l, const float* __restrict__ W1r,
                                               const float* __restrict__ W2l, const float* __restrict__ W2r,
                                               const float* __restrict__ Wrec, unsigned short* __restrict__ dst) {
    int i = blockIdx.x * 256 + threadIdx.x;   // float4 units, total 14336
    int e = i * 4;
    if (e >= 57344) return;
    const float* src; int off;
    if (e < 8192)       { src = W1l;  off = 0; }
    else if (e < 16384) { src = W1r;  off = 8192; }
    else if (e < 32768) { src = W2l;  off = 16384; }
    else if (e < 49152) { src = W2r;  off = 32768; }
    else                { src = Wrec; off = 49152; }
    float4 v = *(const float4*)(src + (e - off));
    unsigned lo = f2bf(v.x) | ((unsigned)f2bf(v.y) << 16);
    unsigned hi = f2bf(v.z) | ((unsigned)f2bf(v.w) << 16);
    *(uint2*)(dst + e) = make_uint2(lo, hi);
}

// ---------------- CSR build (validated path, r4/r14) ----------------

__global__ __launch_bounds__(256) void k_deg(const int* __restrict__ ei, int* __restrict__ deg) {
    int e = blockIdx.x * 256 + threadIdx.x;
    if (e < N_EDGES) {
        int d = ei[N_EDGES + e];
        if ((unsigned)d < N_NODES) atomicAdd(&deg[d], 1);   // no-return atomic: fast
    }
}

__global__ __launch_bounds__(256) void k_scan1(const int* __restrict__ deg,
                                               int* __restrict__ excl,
                                               int* __restrict__ bsum) {
    int gid = blockIdx.x * 256 + threadIdx.x;
    int v = (gid < N_NODES) ? deg[gid] : 0;
    int lane = threadIdx.x & 63, wv = threadIdx.x >> 6;
    int s = v;
    #pragma unroll
    for (int d = 1; d < 64; d <<= 1) {
        int t = __shfl_up(s, d);
        if (lane >= d) s += t;
    }
    __shared__ int wsum[4];
    if (lane == 63) wsum[wv] = s;
    __syncthreads();
    int add = 0;
    #pragma unroll
    for (int w = 0; w < 4; w++) add += (w < wv) ? wsum[w] : 0;
    s += add;
    if (gid < N_NODES) excl[gid] = s - v;
    if (threadIdx.x == 255) bsum[blockIdx.x] = s;
}

__global__ __launch_bounds__(256) void k_scan2(const int* __restrict__ bsum,
                                               int* __restrict__ bpre,
                                               int* __restrict__ offs) {
    int tid = threadIdx.x;
    int v = (tid < NB_SCAN) ? bsum[tid] : 0;
    int lane = tid & 63, wv = tid >> 6;
    int s = v;
    #pragma unroll
    for (int d = 1; d < 64; d <<= 1) {
        int t = __shfl_up(s, d);
        if (lane >= d) s += t;
    }
    __shared__ int wsum[4];
    if (lane == 63) wsum[wv] = s;
    __syncthreads();
    int add = 0;
    #pragma unroll
    for (int w = 0; w < 4; w++) add += (w < wv) ? wsum[w] : 0;
    s += add;
    if (tid < NB_SCAN) bpre[tid] = s - v;
    if (tid == NB_SCAN - 1) offs[N_NODES] = s;
}

__global__ __launch_bounds__(256) void k_scan3(const int* __restrict__ excl,
                                               const int* __restrict__ bpre,
                                               int* __restrict__ offs) {
    int gid = blockIdx.x * 256 + threadIdx.x;
    if (gid < N_NODES) offs[gid] = excl[gid] + bpre[blockIdx.x];
}

__global__ __launch_bounds__(256) void k_fill(const int* __restrict__ ei, const int* __restrict__ offs,
                                              int* __restrict__ cursor, int* __restrict__ csr) {
    int e = blockIdx.x * 256 + threadIdx.x;
    if (e < N_EDGES) {
        int s = ei[e];
        int d = ei[N_EDGES + e];
        if ((unsigned)d < N_NODES && (unsigned)s < N_NODES) {
            int pos = atomicAdd(&cursor[d], 1);   // returning atomic, 50K addrs, ~16 hits: OK
            csr[offs[d] + pos] = s;
        }
    }
}

// ---------------- single-pass mean aggregation (validated r6 shapes) ----------------
// CH=64: halves of the wave take alternating edges, 2 ch/lane, shfl-combine.
__global__ __launch_bounds__(256) void k_agg64b(const unsigned short* __restrict__ X,
                                                const int* __restrict__ csr,
                                                const int* __restrict__ offs,
                                                unsigned short* __restrict__ out) {
    int wid = (blockIdx.x * 256 + threadIdx.x) >> 6;
    int lane = threadIdx.x & 63;
    if (wid >= N_NODES) return;
    int beg = offs[wid], end = offs[wid + 1];
    int degn = end - beg;
    float inv = 1.0f / (float)(degn > 0 ? degn : 1);
    int half = lane >> 5, hl = lane & 31;
    float sx = 0.f, sy = 0.f;
    for (int e = beg + half; e < end; e += 2) {
        int idx = __builtin_nontemporal_load(&csr[e]);
        unsigned v = *(const unsigned*)(X + (size_t)idx * 64 + hl * 2);
        sx += bflo(v); sy += bfhi(v);
    }
    sx += __shfl_xor(sx, 32);
    sy += __shfl_xor(sy, 32);
    if (half == 0) {
        unsigned o = f2bf(sx * inv) | ((unsigned)f2bf(sy * inv) << 16);
        *(unsigned*)(out + (size_t)wid * 64 + hl * 2) = o;
    }
}

// CH=128: full wave per row, 2 ch/lane, sequential pairs.
__global__ __launch_bounds__(256) void k_agg128b(const unsigned short* __restrict__ X,
                                                 const int* __restrict__ csr,
                                                 const int* __restrict__ offs,
                                                 unsigned short* __restrict__ out) {
    int wid = (blockIdx.x * 256 + threadIdx.x) >> 6;
    int lane = threadIdx.x & 63;
    if (wid >= N_NODES) return;
    int beg = offs[wid], end = offs[wid + 1];
    int degn = end - beg;
    float inv = 1.0f / (float)(degn > 0 ? degn : 1);
    float sx = 0.f, sy = 0.f;
    int e = beg;
    for (; e + 2 <= end; e += 2) {
        int i0 = __builtin_nontemporal_load(&csr[e]);
        int i1 = __builtin_nontemporal_load(&csr[e + 1]);
        unsigned a = *(const unsigned*)(X + (size_t)i0 * 128 + lane * 2);
        unsigned b = *(const unsigned*)(X + (size_t)i1 * 128 + lane * 2);
        sx += bflo(a) + bflo(b);
        sy += bfhi(a) + bfhi(b);
    }
    if (e < end) {
        int i0 = __builtin_nontemporal_load(&csr[e]);
        unsigned a = *(const unsigned*)(X + (size_t)i0 * 128 + lane * 2);
        sx += bflo(a); sy += bfhi(a);
    }
    unsigned o = f2bf(sx * inv) | ((unsigned)f2bf(sy * inv) << 16);
    *(unsigned*)(out + (size_t)wid * 128 + lane * 2) = o;
}

// ---------------- bf16 MFMA GEMM, W staged in LDS (XOR-swizzled; validated r10/r14) ----------------

template <int NOUT, int K1, bool DUAL, bool RELU, bool WF32, bool WBF16>
__global__ __launch_bounds__(256) void k_gemm_mfma(const unsigned short* __restrict__ A0,
                                                   const unsigned short* __restrict__ A1,
                                                   const unsigned short* __restrict__ W0,
                                                   const unsigned short* __restrict__ W1,
                                                   const float* __restrict__ bias,
                                                   float* __restrict__ out,
                                                   unsigned short* __restrict__ outb) {
    constexpr int NF = NOUT / 16;
    constexpr int NPH = DUAL ? 2 : 1;
    __shared__ char wlds[NOUT * K1 * 2];   // 16KB or 32KB
    int tid = threadIdx.x;
    int lane = tid & 63;
    int wv = tid >> 6;
    int m0 = blockIdx.x * 64 + wv * 16;
    int col16 = lane & 15;
    int kg = lane >> 4;
    int arow = m0 + col16;
    if (arow >= N_NODES) arow = N_NODES - 1;   // safe load; store guarded

    f32x4 acc[NF] = {};

    #pragma unroll
    for (int ph = 0; ph < NPH; ph++) {
        const unsigned short* Wp = ph ? W1 : W0;
        const unsigned short* Ap = ph ? A1 : A0;
        if (ph) __syncthreads();   // previous phase's LDS reads done
        constexpr int CHUNKS = NOUT * K1 / 8;
        #pragma unroll
        for (int it = 0; it < CHUNKS / 256; it++) {
            int ci = tid + it * 256;
            int j = ci / (K1 / 8);
            int c = (ci % (K1 / 8)) * 8;
            short8 w = *(const short8*)(Wp + (size_t)j * K1 + c);
            int byte = ((j * K1 + c) * 2) ^ ((j & 7) << 4);
            *(short8*)(wlds + byte) = w;
        }
        __syncthreads();
        #pragma unroll
        for (int ks = 0; ks < K1 / 32; ks++) {
            int kk = ks * 32;
            short8 a = *(const short8*)(Ap + (size_t)arow * K1 + kk + kg * 8);
            #pragma unroll
            for (int j = 0; j < NF; j++) {
                int row = j * 16 + col16;
                int byte = ((row * K1 + kk + kg * 8) * 2) ^ ((row & 7) << 4);
                short8 b = *(const short8*)(wlds + byte);
                acc[j] = __builtin_amdgcn_mfma_f32_16x16x32_bf16(a, b, acc[j], 0, 0, 0);
            }
        }
    }

    // C/D layout: col = lane&15, row = (lane>>4)*4 + reg   [verified, learn_hip m89]
    int col = lane & 15;
    int r0 = (lane >> 4) * 4;
    #pragma unroll
    for (int j = 0; j < NF; j++) {
        float bv = bias[j * 16 + col];
        #pragma unroll
        for (int r = 0; r < 4; r++) {
            int grow = m0 + r0 + r;
            if (grow < N_NODES) {
                float v = acc[j][r] + bv;
                if (RELU) v = fmaxf(v, 0.f);
                if (WF32)  out[(size_t)grow * NOUT + j * 16 + col] = v;
                if (WBF16) outb[(size_t)grow * NOUT + j * 16 + col] = f2bf(v);
            }
        }
    }
}

// ---------------- launch ----------------

extern "C" void kernel_launch(void* const* d_in, const int* in_sizes, int n_in,
                              void* d_out, int out_size, void* d_ws, size_t ws_size,
                              hipStream_t stream) {
    const float* x    = (const float*)d_in[0];
    const int*   ei   = (const int*)d_in[1];
    const float* W1l  = (const float*)d_in[2];
    const float* b1l  = (const float*)d_in[3];
    const float* W1r  = (const float*)d_in[4];
    const float* W2l  = (const float*)d_in[5];
    const float* b2l  = (const float*)d_in[6];
    const float* W2r  = (const float*)d_in[7];
    const float* Wrec = (const float*)d_in[8];
    const float* brec = (const float*)d_in[9];

    float* z    = (float*)d_out;                          // [N,128]
    float* xrec = (float*)d_out + (size_t)N_NODES * HID;  // [N,64]

    // workspace layout (peak ~52 MB)
    char* ws = (char*)d_ws;
    int*   deg    = (int*)(ws);                  // 200 KB
    int*   offs   = (int*)(ws + (256u << 10));   // 50001 ints
    int*   cursor = (int*)(ws + (512u << 10));
    int*   excl   = (int*)(ws + (768u << 10));
    int*   bsum   = (int*)(ws + (1024u << 10));  // 196 ints
    int*   bpre   = (int*)(ws + (1028u << 10));  // 196 ints
    int*   csr    = (int*)(ws + (2u << 20));     // 3.2 MB
    unsigned short* wb     = (unsigned short*)(ws + (5632u << 10));  // 114 KB bf16 weights
    unsigned short* xb     = (unsigned short*)(ws + (6u  << 20));    // [N,64]  6.4 MB
    unsigned short* mean1b = (unsigned short*)(ws + (13u << 20));    // [N,64]  (dead after gemm1)
    unsigned short* mean2b = (unsigned short*)(ws + (13u << 20));    // [N,128] reuses mean1b
    unsigned short* hb     = (unsigned short*)(ws + (26u << 20));    // [N,128] 12.8 MB
    unsigned short* zb     = (unsigned short*)(ws + (39u << 20));    // [N,128] 12.8 MB

    unsigned short* W1lb  = wb;
    unsigned short* W1rb  = wb + 8192;
    unsigned short* W2lb  = wb + 16384;
    unsigned short* W2rb  = wb + 32768;
    unsigned short* Wrecb = wb + 49152;

    (void)hipMemsetAsync(deg, 0, N_NODES * sizeof(int), stream);
    (void)hipMemsetAsync(cursor, 0, N_NODES * sizeof(int), stream);

    int egrid = (N_EDGES + 255) / 256;
    int ngrid = (N_NODES + 63) / 64;   // 782
    int agrid = (N_NODES + 3) / 4;     // 12500

    k_cvt_w<<<56, 256, 0, stream>>>(W1l, W1r, W2l, W2r, Wrec, wb);
    k_cvt<<<(800000 + 255) / 256, 256, 0, stream>>>(x, xb, 800000);

    k_deg<<<egrid, 256, 0, stream>>>(ei, deg);
    k_scan1<<<NB_SCAN, 256, 0, stream>>>(deg, excl, bsum);
    k_scan2<<<1, 256, 0, stream>>>(bsum, bpre, offs);
    k_scan3<<<NB_SCAN, 256, 0, stream>>>(excl, bpre, offs);
    k_fill<<<egrid, 256, 0, stream>>>(ei, offs, cursor, csr);

    k_agg64b<<<agrid, 256, 0, stream>>>(xb, csr, offs, mean1b);
    k_gemm_mfma<128, 64, true, true, false, true>
        <<<ngrid, 256, 0, stream>>>(mean1b, xb, W1lb, W1rb, b1l, nullptr, hb);
    k_agg128b<<<agrid, 256, 0, stream>>>(hb, csr, offs, mean2b);
    k_gemm_mfma<128, 128, true, false, true, true>
        <<<ngrid, 256, 0, stream>>>(mean2b, hb, W2lb, W2rb, b2l, z, zb);
    k_gemm_mfma<64, 128, false, false, true, false>
        <<<ngrid, 256, 0, stream>>>(zb, nullptr, Wrecb, nullptr, brec, xrec, nullptr);
}